// Round 12
// baseline (215.078 us; speedup 1.0000x reference)
//
#include <hip/hip_runtime.h>
#include <hip/hip_bf16.h>
#include <math.h>

// Problem constants: B=8, N=2048, F=128, W=64
constexpr int B = 8;
constexpr int N = 2048;
constexpr int F = 128;
constexpr int W = 64;

constexpr int TQ = 128;    // query rows per attention block (8 waves)
constexpr int TK = 128;    // key rows per K-tile iteration (halves barriers)
constexpr int KSPLIT = 4;  // flash-decoding split over keys
constexpr int TILES_PER_SPLIT = (N / TK) / KSPLIT;   // 4

typedef short     bf16x8 __attribute__((ext_vector_type(8)));  // 8 bf16
typedef _Float16  f16x8  __attribute__((ext_vector_type(8)));  // 8 fp16
typedef float     f32x4  __attribute__((ext_vector_type(4)));  // MFMA acc

__device__ inline ushort f2bf(float f) {
  union { float f; uint u; } v; v.f = f;
  uint u = v.u;
  return (ushort)((u + 0x7FFFu + ((u >> 16) & 1u)) >> 16);  // RNE
}
__device__ inline float bf2f(ushort h) {
  union { uint u; float f; } v; v.u = ((uint)h) << 16;
  return v.f;
}

// Barrier that orders LDS only (lgkmcnt), leaving global loads (vmcnt) in
// flight — __syncthreads() would drain vmcnt(0) and kill cross-tile prefetch.
__device__ inline void lgkm_barrier() {
  asm volatile("s_waitcnt lgkmcnt(0)" ::: "memory");
  __builtin_amdgcn_s_barrier();
}

// ---------------------------------------------------------------------------
// prep_w: concatenated transposed weights wt[256][128] fp16.
// wt[n][k] = W*[k][n], n in [0,64)=Q, [64,128)=K, [128,256)=V.
// ---------------------------------------------------------------------------
__global__ __launch_bounds__(256) void prep_w(
    const float* __restrict__ wq, const float* __restrict__ wk,
    const float* __restrict__ wv, _Float16* __restrict__ wt) {
  int gid = blockIdx.x * 256 + threadIdx.x;   // 4096 threads
  int n = gid >> 4;
  int k0 = (gid & 15) * 8;
  _Float16 t[8];
#pragma unroll
  for (int j = 0; j < 8; ++j) {
    int k = k0 + j;
    float val = (n < 64)  ? wq[k * W + n]
              : (n < 128) ? wk[k * W + (n - 64)]
                          : wv[k * F + (n - 128)];
    t[j] = (_Float16)val;
  }
  *(uint4*)&wt[n * 128 + k0] = *(uint4*)t;
}

// ---------------------------------------------------------------------------
// proj: fused QK+V, fp16 MFMA. One block per 32 x-rows (grid 512, 4 waves).
// x staged ONCE into LDS as fp16; waves 0-1 compute Q|K features (fp16 out),
// waves 2-3 compute V features (transposed, bf16 out — PV path stays bf16).
// ---------------------------------------------------------------------------
constexpr int KP = 136;  // 128 + 8 pad (16B align kept, 2-way banks only)

__global__ __launch_bounds__(256) void proj_kernel(
    const float* __restrict__ x, const _Float16* __restrict__ wt,
    _Float16* __restrict__ q16, _Float16* __restrict__ k16,
    ushort* __restrict__ vt_ws) {
  __shared__ _Float16 xs[32][KP];   // 8.7 KB

  const int tid  = threadIdx.x;
  const int wid  = tid >> 6;             // 0..3
  const int lane = tid & 63;
  const int lg = lane >> 4, li = lane & 15;
  const int pass = wid >> 1;             // 0 = QK, 1 = V
  const int rg   = wid & 1;              // row-group within the 32 rows
  const int brow0 = blockIdx.x * 32;
  const int b    = brow0 / N;
  const int nloc = brow0 % N;

  // stage x tile (32 x 128 fp32 -> fp16), fully coalesced
  for (int idx = tid; idx < 32 * 128 / 4; idx += 256) {
    int row = idx >> 5, c4 = idx & 31;
    float4 xv = *(const float4*)&x[(size_t)(brow0 + row) * F + c4 * 4];
    _Float16 h[4] = {(_Float16)xv.x, (_Float16)xv.y,
                     (_Float16)xv.z, (_Float16)xv.w};
    *(float2*)&xs[row][c4 * 4] = *(float2*)h;
  }
  __syncthreads();

  // x fragments for this wave's 16 rows (A/B layouts identical)
  f16x8 xa[4];
#pragma unroll
  for (int kk = 0; kk < 4; ++kk)
    xa[kk] = *(const f16x8*)&xs[rg * 16 + li][kk * 32 + lg * 8];

  f32x4 zero = {0.f, 0.f, 0.f, 0.f};
  f32x4 acc[8];
#pragma unroll
  for (int t = 0; t < 8; ++t) acc[t] = zero;

  const _Float16* wb = wt + (size_t)pass * 128 * 128;

  if (pass == 0) {
    // D[row][feat] = x . wt^T  (x as A, w as B)
#pragma unroll
    for (int kk = 0; kk < 4; ++kk)
#pragma unroll
      for (int nt = 0; nt < 8; ++nt) {
        f16x8 bw = *(const f16x8*)&wb[(nt * 16 + li) * 128 + kk * 32 + lg * 8];
        acc[nt] = __builtin_amdgcn_mfma_f32_16x16x32_f16(xa[kk], bw, acc[nt], 0, 0, 0);
      }
#pragma unroll
    for (int nt = 0; nt < 8; ++nt)
#pragma unroll
      for (int r = 0; r < 4; ++r) {
        int row = brow0 + rg * 16 + lg * 4 + r;
        int c = nt * 16 + li;
        _Float16 hv = (_Float16)acc[nt][r];
        if (nt < 4) q16[row * W + c] = hv;
        else        k16[row * W + (c - 64)] = hv;
      }
  } else {
    // D[feat][row] = (w as A) . (x as B)  -> coalesced transposed V (bf16)
#pragma unroll
    for (int kk = 0; kk < 4; ++kk)
#pragma unroll
      for (int mt = 0; mt < 8; ++mt) {
        f16x8 aw = *(const f16x8*)&wb[(mt * 16 + li) * 128 + kk * 32 + lg * 8];
        acc[mt] = __builtin_amdgcn_mfma_f32_16x16x32_f16(aw, xa[kk], acc[mt], 0, 0, 0);
      }
#pragma unroll
    for (int mt = 0; mt < 8; ++mt)
#pragma unroll
      for (int r = 0; r < 4; ++r) {
        int f = mt * 16 + lg * 4 + r;
        int n = nloc + rg * 16 + li;
        vt_ws[(size_t)b * F * N + (size_t)f * N + n] = f2bf(acc[mt][r]);
      }
  }
}

// ---------------------------------------------------------------------------
// attn: flash attention, K-split, unshifted softmax, S^T orientation.
// TK=128: 4 tiles/split, 8 lgkm-only barriers/block (was 16). PV runs in two
// 64-key halves reusing the wave-private ps scratch (same-wave DS ops are
// in-order — no barrier between halves). Register prefetch keeps next tile's
// global loads in flight across compute. Partials stored bf16.
// Grid (N/128, B, KSPLIT), 512 thr.
// ---------------------------------------------------------------------------
constexpr int LPK = 72;    // 64 + 8 pad (K cols, ps cols)
constexpr int LPV = 136;   // 128 + 8 pad (V^T key cols)

__global__ __launch_bounds__(512) void attn_kernel(
    const _Float16* __restrict__ q16, const _Float16* __restrict__ k16,
    const ushort* __restrict__ vt_ws,
    ushort* __restrict__ op0, ushort* __restrict__ op1,
    ushort* __restrict__ op2, ushort* __restrict__ op3,
    float* __restrict__ lsums) {  // [KSPLIT][B*N]
  __shared__ _Float16 ksh[TK][LPK];    // 18.4 KB  K tile fp16 (128 rows)
  __shared__ ushort  vst[F][LPV];      // 34.8 KB  V^T tile [f][128 keys] bf16
  __shared__ ushort  ps[8][16][LPK];   // 18.4 KB  per-wave P[query][64 keys]

  const int tid  = threadIdx.x;
  const int wid  = tid >> 6;           // 0..7
  const int lane = tid & 63;
  const int lg = lane >> 4, li = lane & 15;
  const int b = blockIdx.y, qt = blockIdx.x, split = blockIdx.z;

  const size_t koffb = (size_t)b * N * W;
  const ushort* vb = vt_ws + (size_t)b * F * N;

  // Q fragments straight from global (this wave's 16 query rows)
  const size_t qrow = (size_t)(b * N + qt * TQ + wid * 16 + li) * W;
  f16x8 qa[2];
  qa[0] = *(const f16x8*)&q16[qrow + lg * 8];
  qa[1] = *(const f16x8*)&q16[qrow + 32 + lg * 8];

  // staging addresses (fixed per thread)
  const int kr0 = tid >> 3,  kr1 = (tid + 512) >> 3, kc8 = tid & 7;  // K rows
  const int vf0 = tid >> 4,  vfs = 512 >> 4;                          // V rows
  const int vc16 = tid & 15;

  // register prefetch buffers for the next tile
  uint4 kra, krb, vra, vrb, vrc, vrd;
  auto load_tile = [&](int kt) {
    const _Float16* kp = k16 + koffb + (size_t)kt * TK * W;
    kra = *(const uint4*)&kp[kr0 * W + kc8 * 8];
    krb = *(const uint4*)&kp[kr1 * W + kc8 * 8];
    const ushort* vp = vb + (size_t)kt * TK;
    vra = *(const uint4*)&vp[(size_t)(vf0 + 0 * vfs) * N + vc16 * 8];
    vrb = *(const uint4*)&vp[(size_t)(vf0 + 1 * vfs) * N + vc16 * 8];
    vrc = *(const uint4*)&vp[(size_t)(vf0 + 2 * vfs) * N + vc16 * 8];
    vrd = *(const uint4*)&vp[(size_t)(vf0 + 3 * vfs) * N + vc16 * 8];
  };

  float l_lane = 0.f;                  // denominator partial for query row li
  f32x4 zero = {0.f, 0.f, 0.f, 0.f};
  f32x4 o_acc[8];
#pragma unroll
  for (int t = 0; t < 8; ++t) o_acc[t] = zero;

  const int kt0 = split * TILES_PER_SPLIT;
  load_tile(kt0);

  for (int kt = kt0; kt < kt0 + TILES_PER_SPLIT; ++kt) {
    // barrier A: all waves done READING ksh/vst of previous tile (lgkm only)
    lgkm_barrier();
    // drain prefetched regs into LDS (compiler inserts the vmcnt wait here)
    *(uint4*)&ksh[kr0][kc8 * 8] = kra;
    *(uint4*)&ksh[kr1][kc8 * 8] = krb;
    *(uint4*)&vst[vf0 + 0 * vfs][vc16 * 8] = vra;
    *(uint4*)&vst[vf0 + 1 * vfs][vc16 * 8] = vrb;
    *(uint4*)&vst[vf0 + 2 * vfs][vc16 * 8] = vrc;
    *(uint4*)&vst[vf0 + 3 * vfs][vc16 * 8] = vrd;
    // issue next tile's loads NOW — they stay in flight across compute
    if (kt + 1 < kt0 + TILES_PER_SPLIT) load_tile(kt + 1);
    // barrier B: LDS writes visible (lgkm only; vmcnt stays outstanding)
    lgkm_barrier();

    // ---- S^T = K Q^T over 128 keys (single fp16 MFMA per product) ----
    f32x4 s_acc[8];
#pragma unroll
    for (int nt = 0; nt < 8; ++nt) s_acc[nt] = zero;
#pragma unroll
    for (int kk = 0; kk < 2; ++kk)
#pragma unroll
      for (int nt = 0; nt < 8; ++nt) {
        f16x8 kf = *(const f16x8*)&ksh[nt * 16 + li][kk * 32 + lg * 8];
        s_acc[nt] = __builtin_amdgcn_mfma_f32_16x16x32_f16(kf, qa[kk], s_acc[nt], 0, 0, 0);
      }

    // ---- softmax + PV in two 64-key halves (ps reused; same-wave RAW/WAR
    // ordered by in-order DS + compiler lgkmcnt) ----
#pragma unroll
    for (int half = 0; half < 2; ++half) {
#pragma unroll
      for (int nt2 = 0; nt2 < 4; ++nt2) {
        int nt = half * 4 + nt2;
        ushort ph[4];
#pragma unroll
        for (int r = 0; r < 4; ++r) {
          float p = __expf(s_acc[nt][r]);
          ph[r] = f2bf(p);
          l_lane += bf2f(ph[r]);   // denominator consistent with bf16 numerator
        }
        *(float2*)&ps[wid][li][nt2 * 16 + lg * 4] = *(float2*)ph;
      }
#pragma unroll
      for (int kk = 0; kk < 2; ++kk) {
        bf16x8 pa = *(const bf16x8*)&ps[wid][li][kk * 32 + lg * 8];
#pragma unroll
        for (int ft = 0; ft < 8; ++ft) {
          bf16x8 vf = *(const bf16x8*)&vst[ft * 16 + li][half * 64 + kk * 32 + lg * 8];
          o_acc[ft] = __builtin_amdgcn_mfma_f32_16x16x32_bf16(pa, vf, o_acc[ft], 0, 0, 0);
        }
      }
    }
  }

  // ---- finish l: sum across the 4 lg-lanes sharing query row li ----
  l_lane += __shfl_xor(l_lane, 16, 64);
  l_lane += __shfl_xor(l_lane, 32, 64);

  // ---- epilogue: store UNNORMALIZED bf16 partial + l per row ----
  ushort* opb = (split == 0) ? op0 : (split == 1) ? op1 : (split == 2) ? op2 : op3;
  ushort* ob = opb + (size_t)(b * N + qt * TQ) * F;
#pragma unroll
  for (int r = 0; r < 4; ++r) {
    int row = wid * 16 + lg * 4 + r;
#pragma unroll
    for (int ft = 0; ft < 8; ++ft)
      ob[row * F + ft * 16 + li] = f2bf(o_acc[ft][r]);
  }
  if (lg == 0) {
    size_t gr = (size_t)split * B * N + (size_t)(b * N + qt * TQ) + wid * 16 + li;
    lsums[gr] = l_lane;
  }
}

// ---------------------------------------------------------------------------
// combine: merge the four bf16 K-split partials. 2 rows per 256-thread block.
// ---------------------------------------------------------------------------
__global__ __launch_bounds__(256) void combine_kernel(
    const ushort* __restrict__ op0, const ushort* __restrict__ op1,
    const ushort* __restrict__ op2, const ushort* __restrict__ op3,
    const float* __restrict__ lsums, float* __restrict__ out) {
  const int gr  = blockIdx.x * 2 + (threadIdx.x >> 7);
  const int col = threadIdx.x & 127;
  constexpr size_t BN = (size_t)B * N;
  const float l = lsums[gr] + lsums[BN + gr] + lsums[2 * BN + gr] + lsums[3 * BN + gr];
  const float inv = 1.f / l;
  const size_t idx = (size_t)gr * F + col;
  out[idx] = (bf2f(op0[idx]) + bf2f(op1[idx]) + bf2f(op2[idx]) + bf2f(op3[idx])) * inv;
}

// ---------------------------------------------------------------------------
// Launch
// ---------------------------------------------------------------------------
extern "C" void kernel_launch(void* const* d_in, const int* in_sizes, int n_in,
                              void* d_out, int out_size, void* d_ws, size_t ws_size,
                              hipStream_t stream) {
  // setup_inputs order: x, adj(unused), w_key, w_value, w_query
  const float* x  = (const float*)d_in[0];
  const float* wk = (const float*)d_in[2];
  const float* wv = (const float*)d_in[3];
  const float* wq = (const float*)d_in[4];
  float* out = (float*)d_out;

  constexpr size_t BNW = (size_t)B * N * W;   // 1,048,576
  constexpr size_t BNF = (size_t)B * N * F;   // 2,097,152
  _Float16* q16 = (_Float16*)d_ws;            // BNW fp16
  _Float16* k16 = q16 + BNW;                  // BNW fp16
  ushort*   vt  = (ushort*)(k16 + BNW);       // BNF u16
  _Float16* wt  = (_Float16*)(vt + BNF);      // 256*128 fp16
  ushort*   op0 = (ushort*)(wt + 32768);      // BNF u16 partials x4
  ushort*   op1 = op0 + BNF;
  ushort*   op2 = op1 + BNF;
  ushort*   op3 = op2 + BNF;
  float*    ls  = (float*)(op3 + BNF);        // KSPLIT*B*N fp32
  // total ~25 MB

  prep_w<<<16, 256, 0, stream>>>(wq, wk, wv, wt);
  proj_kernel<<<(B * N) / 32, 256, 0, stream>>>(x, wt, q16, k16, vt);
  dim3 grid(N / TQ, B, KSPLIT);
  attn_kernel<<<grid, 512, 0, stream>>>(q16, k16, vt, op0, op1, op2, op3, ls);
  combine_kernel<<<B * N / 2, 256, 0, stream>>>(op0, op1, op2, op3, ls, out);
}

// Round 13
// 211.427 us; speedup vs baseline: 1.0173x; 1.0173x over previous
//
#include <hip/hip_runtime.h>
#include <hip/hip_bf16.h>
#include <math.h>

// Problem constants: B=8, N=2048, F=128, W=64
constexpr int B = 8;
constexpr int N = 2048;
constexpr int F = 128;
constexpr int W = 64;

constexpr int TQ = 128;    // query rows per attention block (8 waves)
constexpr int TK = 64;     // key rows per K-tile iteration (R12: 128 regressed)
constexpr int KSPLIT = 4;  // flash-decoding split over keys
constexpr int TILES_PER_SPLIT = (N / TK) / KSPLIT;   // 8

typedef short     bf16x8 __attribute__((ext_vector_type(8)));  // 8 bf16
typedef _Float16  f16x8  __attribute__((ext_vector_type(8)));  // 8 fp16
typedef float     f32x4  __attribute__((ext_vector_type(4)));  // MFMA acc

__device__ inline ushort f2bf(float f) {
  union { float f; uint u; } v; v.f = f;
  uint u = v.u;
  return (ushort)((u + 0x7FFFu + ((u >> 16) & 1u)) >> 16);  // RNE
}
__device__ inline float bf2f(ushort h) {
  union { uint u; float f; } v; v.u = ((uint)h) << 16;
  return v.f;
}

// Barrier that orders LDS only (lgkmcnt), leaving global loads (vmcnt) in
// flight — __syncthreads() would drain vmcnt(0) and kill cross-tile prefetch.
__device__ inline void lgkm_barrier() {
  asm volatile("s_waitcnt lgkmcnt(0)" ::: "memory");
  __builtin_amdgcn_s_barrier();
}

// ---------------------------------------------------------------------------
// prep_w: concatenated transposed weights wt[256][128] fp16.
// wt[n][k] = W*[k][n], n in [0,64)=Q, [64,128)=K, [128,256)=V.
// ---------------------------------------------------------------------------
__global__ __launch_bounds__(256) void prep_w(
    const float* __restrict__ wq, const float* __restrict__ wk,
    const float* __restrict__ wv, _Float16* __restrict__ wt) {
  int gid = blockIdx.x * 256 + threadIdx.x;   // 4096 threads
  int n = gid >> 4;
  int k0 = (gid & 15) * 8;
  _Float16 t[8];
#pragma unroll
  for (int j = 0; j < 8; ++j) {
    int k = k0 + j;
    float val = (n < 64)  ? wq[k * W + n]
              : (n < 128) ? wk[k * W + (n - 64)]
                          : wv[k * F + (n - 128)];
    t[j] = (_Float16)val;
  }
  *(uint4*)&wt[n * 128 + k0] = *(uint4*)t;
}

// ---------------------------------------------------------------------------
// proj: fused QK+V, fp16 MFMA. One block per 64 x-rows (grid 256 = 1/CU,
// all-resident). 4 waves: waves 0-1 = QK pass, waves 2-3 = V pass; each wave
// owns 32 rows (two A-fragment sets) and reuses every weight B-fragment for
// 2 MFMAs -> weight L2 traffic and per-MFMA issue overhead halved vs 16-row
// waves. x staged ONCE into LDS (fusion keeps x HBM reads at 64 MB).
// ---------------------------------------------------------------------------
constexpr int KP = 136;  // 128 + 8 pad (16B align kept, 2-way banks only)

__global__ __launch_bounds__(256) void proj_kernel(
    const float* __restrict__ x, const _Float16* __restrict__ wt,
    _Float16* __restrict__ q16, _Float16* __restrict__ k16,
    ushort* __restrict__ vt_ws) {
  __shared__ _Float16 xs[64][KP];   // 17.4 KB

  const int tid  = threadIdx.x;
  const int wid  = tid >> 6;             // 0..3
  const int lane = tid & 63;
  const int lg = lane >> 4, li = lane & 15;
  const int pass = wid >> 1;             // 0 = QK, 1 = V
  const int rg   = (wid & 1) * 32;       // 32-row group within the 64 rows
  const int brow0 = blockIdx.x * 64;
  const int b    = brow0 / N;
  const int nloc = brow0 % N;

  // stage x tile (64 x 128 fp32 -> fp16), fully coalesced
  for (int idx = tid; idx < 64 * 128 / 4; idx += 256) {
    int row = idx >> 5, c4 = idx & 31;
    float4 xv = *(const float4*)&x[(size_t)(brow0 + row) * F + c4 * 4];
    _Float16 h[4] = {(_Float16)xv.x, (_Float16)xv.y,
                     (_Float16)xv.z, (_Float16)xv.w};
    *(float2*)&xs[row][c4 * 4] = *(float2*)h;
  }
  __syncthreads();

  // two A-fragment sets: rows rg+li and rg+16+li
  f16x8 xa0[4], xa1[4];
#pragma unroll
  for (int kk = 0; kk < 4; ++kk) {
    xa0[kk] = *(const f16x8*)&xs[rg + li][kk * 32 + lg * 8];
    xa1[kk] = *(const f16x8*)&xs[rg + 16 + li][kk * 32 + lg * 8];
  }

  f32x4 zero = {0.f, 0.f, 0.f, 0.f};
  f32x4 acc0[8], acc1[8];
#pragma unroll
  for (int t = 0; t < 8; ++t) { acc0[t] = zero; acc1[t] = zero; }

  const _Float16* wb = wt + (size_t)pass * 128 * 128;

  if (pass == 0) {
    // D[row][feat] = x . wt^T  (x as A, w as B); each B-frag used twice
#pragma unroll
    for (int kk = 0; kk < 4; ++kk)
#pragma unroll
      for (int nt = 0; nt < 8; ++nt) {
        f16x8 bw = *(const f16x8*)&wb[(nt * 16 + li) * 128 + kk * 32 + lg * 8];
        acc0[nt] = __builtin_amdgcn_mfma_f32_16x16x32_f16(xa0[kk], bw, acc0[nt], 0, 0, 0);
        acc1[nt] = __builtin_amdgcn_mfma_f32_16x16x32_f16(xa1[kk], bw, acc1[nt], 0, 0, 0);
      }
#pragma unroll
    for (int nt = 0; nt < 8; ++nt)
#pragma unroll
      for (int r = 0; r < 4; ++r) {
        int c = nt * 16 + li;
        int row0 = brow0 + rg + lg * 4 + r;
        int row1 = row0 + 16;
        _Float16 h0 = (_Float16)acc0[nt][r];
        _Float16 h1 = (_Float16)acc1[nt][r];
        if (nt < 4) {
          q16[row0 * W + c] = h0; q16[row1 * W + c] = h1;
        } else {
          k16[row0 * W + (c - 64)] = h0; k16[row1 * W + (c - 64)] = h1;
        }
      }
  } else {
    // D[feat][row] = (w as A) . (x as B)  -> coalesced transposed V (bf16)
#pragma unroll
    for (int kk = 0; kk < 4; ++kk)
#pragma unroll
      for (int mt = 0; mt < 8; ++mt) {
        f16x8 aw = *(const f16x8*)&wb[(mt * 16 + li) * 128 + kk * 32 + lg * 8];
        acc0[mt] = __builtin_amdgcn_mfma_f32_16x16x32_f16(aw, xa0[kk], acc0[mt], 0, 0, 0);
        acc1[mt] = __builtin_amdgcn_mfma_f32_16x16x32_f16(aw, xa1[kk], acc1[mt], 0, 0, 0);
      }
    ushort* vbase = vt_ws + (size_t)b * F * N;
#pragma unroll
    for (int mt = 0; mt < 8; ++mt)
#pragma unroll
      for (int r = 0; r < 4; ++r) {
        int f = mt * 16 + lg * 4 + r;
        int n0 = nloc + rg + li;
        vbase[(size_t)f * N + n0]      = f2bf(acc0[mt][r]);
        vbase[(size_t)f * N + n0 + 16] = f2bf(acc1[mt][r]);
      }
  }
}

// ---------------------------------------------------------------------------
// attn: flash attention, K-split, unshifted softmax, S^T orientation.
// (R11 structure — best measured. TK=64, lgkm-only barriers, register
// prefetch keeps next tile's global loads in flight across compute.)
// Grid (N/128, B, KSPLIT), 512 thr; bf16 partials.
// ---------------------------------------------------------------------------
constexpr int LP = 72;   // 64 + 8 pad

__global__ __launch_bounds__(512) void attn_kernel(
    const _Float16* __restrict__ q16, const _Float16* __restrict__ k16,
    const ushort* __restrict__ vt_ws,
    ushort* __restrict__ op0, ushort* __restrict__ op1,
    ushort* __restrict__ op2, ushort* __restrict__ op3,
    float* __restrict__ lsums) {  // [KSPLIT][B*N]
  __shared__ _Float16 ksh[TK][LP];     //  9.2 KB  K tile fp16
  __shared__ ushort  vst[F][LP];       // 18.4 KB  V^T tile [f][key] bf16
  __shared__ ushort  ps[8][16][LP];    // 18.4 KB  per-wave P[query][key] bf16

  const int tid  = threadIdx.x;
  const int wid  = tid >> 6;           // 0..7
  const int lane = tid & 63;
  const int lg = lane >> 4, li = lane & 15;
  const int b = blockIdx.y, qt = blockIdx.x, split = blockIdx.z;

  const size_t koffb = (size_t)b * N * W;
  const ushort* vb = vt_ws + (size_t)b * F * N;

  // Q fragments straight from global (this wave's 16 query rows)
  const size_t qrow = (size_t)(b * N + qt * TQ + wid * 16 + li) * W;
  f16x8 qa[2];
  qa[0] = *(const f16x8*)&q16[qrow + lg * 8];
  qa[1] = *(const f16x8*)&q16[qrow + 32 + lg * 8];

  // staging addresses (fixed per thread)
  const int krow = tid >> 3, kc8 = tid & 7;           // K chunk
  const int vf0 = tid >> 3, vf1 = (tid + 512) >> 3;   // V chunks
  const int vc8 = tid & 7;

  // register prefetch buffers for the next tile
  uint4 kr, vr0, vr1;
  auto load_tile = [&](int kt) {
    kr  = *(const uint4*)&k16[koffb + (size_t)kt * TK * W + krow * W + kc8 * 8];
    vr0 = *(const uint4*)&vb[(size_t)vf0 * N + kt * TK + vc8 * 8];
    vr1 = *(const uint4*)&vb[(size_t)vf1 * N + kt * TK + vc8 * 8];
  };

  float l_lane = 0.f;                  // denominator partial for query row li
  f32x4 zero = {0.f, 0.f, 0.f, 0.f};
  f32x4 o_acc[8];
#pragma unroll
  for (int t = 0; t < 8; ++t) o_acc[t] = zero;

  const int kt0 = split * TILES_PER_SPLIT;
  load_tile(kt0);

  for (int kt = kt0; kt < kt0 + TILES_PER_SPLIT; ++kt) {
    // barrier A: all waves done READING ksh/vst of previous tile (lgkm only)
    lgkm_barrier();
    // drain prefetched regs into LDS (compiler inserts the vmcnt wait here)
    *(uint4*)&ksh[krow][kc8 * 8] = kr;
    *(uint4*)&vst[vf0][vc8 * 8] = vr0;
    *(uint4*)&vst[vf1][vc8 * 8] = vr1;
    // issue next tile's loads NOW — they stay in flight across compute
    if (kt + 1 < kt0 + TILES_PER_SPLIT) load_tile(kt + 1);
    // barrier B: LDS writes visible (lgkm only; vmcnt stays outstanding)
    lgkm_barrier();

    // ---- S^T = K Q^T (single fp16 MFMA per product) ----
    f32x4 s_acc[4];
#pragma unroll
    for (int nt = 0; nt < 4; ++nt) s_acc[nt] = zero;
#pragma unroll
    for (int kk = 0; kk < 2; ++kk)
#pragma unroll
      for (int nt = 0; nt < 4; ++nt) {
        f16x8 kf = *(const f16x8*)&ksh[nt * 16 + li][kk * 32 + lg * 8];
        s_acc[nt] = __builtin_amdgcn_mfma_f32_16x16x32_f16(kf, qa[kk], s_acc[nt], 0, 0, 0);
      }

    // ---- unshifted softmax: lane (lg,li) holds s(query li, key nt*16+lg*4+r).
#pragma unroll
    for (int nt = 0; nt < 4; ++nt) {
      ushort ph[4];
#pragma unroll
      for (int r = 0; r < 4; ++r) {
        float p = __expf(s_acc[nt][r]);
        ph[r] = f2bf(p);
        l_lane += bf2f(ph[r]);   // denominator consistent with bf16 numerator
      }
      *(float2*)&ps[wid][li][nt * 16 + lg * 4] = *(float2*)ph;
    }

    // ---- O += P V (wave-private P scratch; same-wave RAW via lgkmcnt) ----
#pragma unroll
    for (int kk = 0; kk < 2; ++kk) {
      bf16x8 pa = *(const bf16x8*)&ps[wid][li][kk * 32 + lg * 8];
#pragma unroll
      for (int ft = 0; ft < 8; ++ft) {
        bf16x8 vf = *(const bf16x8*)&vst[ft * 16 + li][kk * 32 + lg * 8];
        o_acc[ft] = __builtin_amdgcn_mfma_f32_16x16x32_bf16(pa, vf, o_acc[ft], 0, 0, 0);
      }
    }
  }

  // ---- finish l: sum across the 4 lg-lanes sharing query row li ----
  l_lane += __shfl_xor(l_lane, 16, 64);
  l_lane += __shfl_xor(l_lane, 32, 64);

  // ---- epilogue: store UNNORMALIZED bf16 partial + l per row ----
  ushort* opb = (split == 0) ? op0 : (split == 1) ? op1 : (split == 2) ? op2 : op3;
  ushort* ob = opb + (size_t)(b * N + qt * TQ) * F;
#pragma unroll
  for (int r = 0; r < 4; ++r) {
    int row = wid * 16 + lg * 4 + r;
#pragma unroll
    for (int ft = 0; ft < 8; ++ft)
      ob[row * F + ft * 16 + li] = f2bf(o_acc[ft][r]);
  }
  if (lg == 0) {
    size_t gr = (size_t)split * B * N + (size_t)(b * N + qt * TQ) + wid * 16 + li;
    lsums[gr] = l_lane;
  }
}

// ---------------------------------------------------------------------------
// combine: merge the four bf16 K-split partials. 2 rows per 256-thread block.
// ---------------------------------------------------------------------------
__global__ __launch_bounds__(256) void combine_kernel(
    const ushort* __restrict__ op0, const ushort* __restrict__ op1,
    const ushort* __restrict__ op2, const ushort* __restrict__ op3,
    const float* __restrict__ lsums, float* __restrict__ out) {
  const int gr  = blockIdx.x * 2 + (threadIdx.x >> 7);
  const int col = threadIdx.x & 127;
  constexpr size_t BN = (size_t)B * N;
  const float l = lsums[gr] + lsums[BN + gr] + lsums[2 * BN + gr] + lsums[3 * BN + gr];
  const float inv = 1.f / l;
  const size_t idx = (size_t)gr * F + col;
  out[idx] = (bf2f(op0[idx]) + bf2f(op1[idx]) + bf2f(op2[idx]) + bf2f(op3[idx])) * inv;
}

// ---------------------------------------------------------------------------
// Launch
// ---------------------------------------------------------------------------
extern "C" void kernel_launch(void* const* d_in, const int* in_sizes, int n_in,
                              void* d_out, int out_size, void* d_ws, size_t ws_size,
                              hipStream_t stream) {
  // setup_inputs order: x, adj(unused), w_key, w_value, w_query
  const float* x  = (const float*)d_in[0];
  const float* wk = (const float*)d_in[2];
  const float* wv = (const float*)d_in[3];
  const float* wq = (const float*)d_in[4];
  float* out = (float*)d_out;

  constexpr size_t BNW = (size_t)B * N * W;   // 1,048,576
  constexpr size_t BNF = (size_t)B * N * F;   // 2,097,152
  _Float16* q16 = (_Float16*)d_ws;            // BNW fp16
  _Float16* k16 = q16 + BNW;                  // BNW fp16
  ushort*   vt  = (ushort*)(k16 + BNW);       // BNF u16
  _Float16* wt  = (_Float16*)(vt + BNF);      // 256*128 fp16
  ushort*   op0 = (ushort*)(wt + 32768);      // BNF u16 partials x4
  ushort*   op1 = op0 + BNF;
  ushort*   op2 = op1 + BNF;
  ushort*   op3 = op2 + BNF;
  float*    ls  = (float*)(op3 + BNF);        // KSPLIT*B*N fp32
  // total ~25 MB

  prep_w<<<16, 256, 0, stream>>>(wq, wk, wv, wt);
  proj_kernel<<<(B * N) / 64, 256, 0, stream>>>(x, wt, q16, k16, vt);
  dim3 grid(N / TQ, B, KSPLIT);
  attn_kernel<<<grid, 512, 0, stream>>>(q16, k16, vt, op0, op1, op2, op3, ls);
  combine_kernel<<<B * N / 2, 256, 0, stream>>>(op0, op1, op2, op3, ls, out);
}